// Round 1
// baseline (3569.859 us; speedup 1.0000x reference)
//
#include <hip/hip_runtime.h>
#include <hip/hip_bf16.h>

#define GN 100000
#define GE 600000

// ---------------------------------------------------------------------------
// Generic fp32 GEMM: C[M, OC] (ldC) = A[M, IC] (ldA) @ W[OC, IC]^T + bias
// Block 256 threads, 64x64 output tile, 4x4 micro-tile per thread, BK=16.
// OC must be a multiple of 64 (here 128 or 64). IC multiple of 16.
// ---------------------------------------------------------------------------
__global__ __launch_bounds__(256) void gemm_bias(
    const float* __restrict__ A, int ldA,
    const float* __restrict__ W,      // [OC, IC] row-major
    const float* __restrict__ bias,   // [OC]
    float* __restrict__ C, int ldC,
    int M, int OC, int IC)
{
    __shared__ float As[16][68];   // [k][m], pad 68 keeps float4 alignment (68*4=272=17*16)
    __shared__ float Bs[16][68];   // [k][n]

    const int tid  = threadIdx.x;
    const int row0 = blockIdx.x * 64;
    const int col0 = blockIdx.y * 64;

    // staging: each thread loads one float4 of A and one of W per K-tile
    const int lr = tid >> 2;          // 0..63 (row within tile / W row)
    const int lk = (tid & 3) * 4;     // 0,4,8,12 (k offset)

    // micro-tile coordinates
    const int mr = (tid >> 4) * 4;    // 0..60
    const int mc = (tid & 15) * 4;    // 0..60

    float acc[4][4] = {};

    for (int k0 = 0; k0 < IC; k0 += 16) {
        // A tile (guard M edge: last row-block has 32 valid rows)
        float4 av = make_float4(0.f, 0.f, 0.f, 0.f);
        const int ar = row0 + lr;
        if (ar < M) av = *(const float4*)(A + (size_t)ar * ldA + k0 + lk);
        As[lk + 0][lr] = av.x; As[lk + 1][lr] = av.y;
        As[lk + 2][lr] = av.z; As[lk + 3][lr] = av.w;

        // W tile (col0+lr < OC always: OC is a multiple of 64)
        const float4 bv = *(const float4*)(W + (size_t)(col0 + lr) * IC + k0 + lk);
        Bs[lk + 0][lr] = bv.x; Bs[lk + 1][lr] = bv.y;
        Bs[lk + 2][lr] = bv.z; Bs[lk + 3][lr] = bv.w;

        __syncthreads();

#pragma unroll
        for (int k = 0; k < 16; ++k) {
            const float4 a = *(const float4*)&As[k][mr];
            const float4 b = *(const float4*)&Bs[k][mc];
            acc[0][0] += a.x * b.x; acc[0][1] += a.x * b.y; acc[0][2] += a.x * b.z; acc[0][3] += a.x * b.w;
            acc[1][0] += a.y * b.x; acc[1][1] += a.y * b.y; acc[1][2] += a.y * b.z; acc[1][3] += a.y * b.w;
            acc[2][0] += a.z * b.x; acc[2][1] += a.z * b.y; acc[2][2] += a.z * b.z; acc[2][3] += a.z * b.w;
            acc[3][0] += a.w * b.x; acc[3][1] += a.w * b.y; acc[3][2] += a.w * b.z; acc[3][3] += a.w * b.w;
        }
        __syncthreads();
    }

    const float4 bb = *(const float4*)(bias + col0 + mc);
#pragma unroll
    for (int i = 0; i < 4; ++i) {
        const int row = row0 + mr + i;
        if (row < M) {
            float4 o;
            o.x = acc[i][0] + bb.x; o.y = acc[i][1] + bb.y;
            o.z = acc[i][2] + bb.z; o.w = acc[i][3] + bb.w;
            *(float4*)(C + (size_t)row * ldC + col0 + mc) = o;
        }
    }
}

// ---------------------------------------------------------------------------
// agg[v][0:128] = h[v][0:128]  (h has leading dim 512 inside cat buffer)
// one thread per float4 -> GN*32 threads
// ---------------------------------------------------------------------------
__global__ __launch_bounds__(256) void init_agg(const float* __restrict__ h,
                                                float* __restrict__ agg)
{
    const int t = blockIdx.x * blockDim.x + threadIdx.x;
    if (t >= GN * 32) return;
    const int v = t >> 5;
    const int q = (t & 31) << 2;
    *(float4*)(agg + (size_t)v * 128 + q) =
        *(const float4*)(h + (size_t)v * 512 + q);
}

// ---------------------------------------------------------------------------
// agg[dst[e]][:] += h[src[e]][:]   (messages src -> dst)
// 32 threads per edge, each handles one float4 (4 fp32 atomics)
// ---------------------------------------------------------------------------
__global__ __launch_bounds__(256) void scatter_add(const float* __restrict__ h,
                                                   const int* __restrict__ src,
                                                   const int* __restrict__ dst,
                                                   float* __restrict__ agg)
{
    const int t = blockIdx.x * blockDim.x + threadIdx.x;
    const int e = t >> 5;
    if (e >= GE) return;
    const int q = (t & 31) << 2;
    const int s = src[e];
    const int d = dst[e];
    const float4 v = *(const float4*)(h + (size_t)s * 512 + q);
    float* o = agg + (size_t)d * 128 + q;
    atomicAdd(o + 0, v.x);
    atomicAdd(o + 1, v.y);
    atomicAdd(o + 2, v.z);
    atomicAdd(o + 3, v.w);
}

// ---------------------------------------------------------------------------
// in-place softmax over rows of 64; one wave (64 lanes) per row
// ---------------------------------------------------------------------------
__global__ __launch_bounds__(256) void softmax64(float* __restrict__ out)
{
    const int w = (blockIdx.x * blockDim.x + threadIdx.x) >> 6;
    const int lane = threadIdx.x & 63;
    if (w >= GN) return;
    float* p = out + (size_t)w * 64;
    const float v = p[lane];
    float m = v;
#pragma unroll
    for (int off = 32; off > 0; off >>= 1) m = fmaxf(m, __shfl_xor(m, off));
    const float e = __expf(v - m);
    float s = e;
#pragma unroll
    for (int off = 32; off > 0; off >>= 1) s += __shfl_xor(s, off);
    p[lane] = e / s;
}

extern "C" void kernel_launch(void* const* d_in, const int* in_sizes, int n_in,
                              void* d_out, int out_size, void* d_ws, size_t ws_size,
                              hipStream_t stream)
{
    const float* x       = (const float*)d_in[0];
    const int*   src     = (const int*)d_in[1];            // edge_index[0]
    const int*   dst     = ((const int*)d_in[1]) + GE;     // edge_index[1]
    const float* W_in    = (const float*)d_in[2];
    const float* b_in    = (const float*)d_in[3];
    const float* W_convs = (const float*)d_in[4];          // [3,128,128]
    const float* b_convs = (const float*)d_in[5];          // [3,128]
    const float* W_out   = (const float*)d_in[6];          // [64,512]
    const float* b_out   = (const float*)d_in[7];
    float*       out     = (float*)d_out;                  // [GN,64]

    // workspace: cat [GN,512] fp32 (hidden states as concat blocks) + agg [GN,128]
    float* cat = (float*)d_ws;
    float* agg = cat + (size_t)GN * 512;

    const dim3 blk(256);
    const dim3 g128((GN + 63) / 64, 128 / 64);   // 1563 x 2
    const dim3 g64((GN + 63) / 64, 1);           // final GEMM, OC=64
    const int copy_blocks    = (GN * 32 + 255) / 256;
    const int scatter_blocks = (GE * 32 + 255) / 256;
    const int softmax_blocks = (GN + 3) / 4;     // 4 rows/block (4 waves)

    // 1. input projection -> cat block 0
    gemm_bias<<<g128, blk, 0, stream>>>(x, 128, W_in, b_in, cat, 512, GN, 128, 128);

    // 2. three GIN layers
    for (int i = 0; i < 3; ++i) {
        const float* h = cat + i * 128;          // current hidden block, ld 512
        init_agg<<<copy_blocks, blk, 0, stream>>>(h, agg);                 // self term
        scatter_add<<<scatter_blocks, blk, 0, stream>>>(h, src, dst, agg); // + neighbors
        gemm_bias<<<g128, blk, 0, stream>>>(agg, 128,
                                            W_convs + (size_t)i * 128 * 128,
                                            b_convs + (size_t)i * 128,
                                            cat + (i + 1) * 128, 512, GN, 128, 128);
    }

    // 3. output projection (reads full cat, ld 512) -> d_out, then softmax in-place
    gemm_bias<<<g64, blk, 0, stream>>>(cat, 512, W_out, b_out, out, 64, GN, 64, 512);
    softmax64<<<softmax_blocks, blk, 0, stream>>>(out);
}

// Round 2
// 770.669 us; speedup vs baseline: 4.6322x; 4.6322x over previous
//
#include <hip/hip_runtime.h>
#include <hip/hip_bf16.h>

#define GN 100000
#define GE 600000
#define SCAN_NBLK 98   // ceil(GN / 1024)

// ---------------------------------------------------------------------------
// Generic fp32 GEMM: C[M, OC] (ldC) = A[M, IC] (ldA) @ W[OC, IC]^T + bias
// Block 256 threads, 64x64 output tile, 4x4 micro-tile per thread, BK=16.
// ---------------------------------------------------------------------------
__global__ __launch_bounds__(256) void gemm_bias(
    const float* __restrict__ A, int ldA,
    const float* __restrict__ W,      // [OC, IC] row-major
    const float* __restrict__ bias,   // [OC]
    float* __restrict__ C, int ldC,
    int M, int OC, int IC)
{
    __shared__ float As[16][68];
    __shared__ float Bs[16][68];

    const int tid  = threadIdx.x;
    const int row0 = blockIdx.x * 64;
    const int col0 = blockIdx.y * 64;

    const int lr = tid >> 2;          // 0..63
    const int lk = (tid & 3) * 4;     // 0,4,8,12

    const int mr = (tid >> 4) * 4;
    const int mc = (tid & 15) * 4;

    float acc[4][4] = {};

    for (int k0 = 0; k0 < IC; k0 += 16) {
        float4 av = make_float4(0.f, 0.f, 0.f, 0.f);
        const int ar = row0 + lr;
        if (ar < M) av = *(const float4*)(A + (size_t)ar * ldA + k0 + lk);
        As[lk + 0][lr] = av.x; As[lk + 1][lr] = av.y;
        As[lk + 2][lr] = av.z; As[lk + 3][lr] = av.w;

        const float4 bv = *(const float4*)(W + (size_t)(col0 + lr) * IC + k0 + lk);
        Bs[lk + 0][lr] = bv.x; Bs[lk + 1][lr] = bv.y;
        Bs[lk + 2][lr] = bv.z; Bs[lk + 3][lr] = bv.w;

        __syncthreads();

#pragma unroll
        for (int k = 0; k < 16; ++k) {
            const float4 a = *(const float4*)&As[k][mr];
            const float4 b = *(const float4*)&Bs[k][mc];
            acc[0][0] += a.x * b.x; acc[0][1] += a.x * b.y; acc[0][2] += a.x * b.z; acc[0][3] += a.x * b.w;
            acc[1][0] += a.y * b.x; acc[1][1] += a.y * b.y; acc[1][2] += a.y * b.z; acc[1][3] += a.y * b.w;
            acc[2][0] += a.z * b.x; acc[2][1] += a.z * b.y; acc[2][2] += a.z * b.z; acc[2][3] += a.z * b.w;
            acc[3][0] += a.w * b.x; acc[3][1] += a.w * b.y; acc[3][2] += a.w * b.z; acc[3][3] += a.w * b.w;
        }
        __syncthreads();
    }

    const float4 bb = *(const float4*)(bias + col0 + mc);
#pragma unroll
    for (int i = 0; i < 4; ++i) {
        const int row = row0 + mr + i;
        if (row < M) {
            float4 o;
            o.x = acc[i][0] + bb.x; o.y = acc[i][1] + bb.y;
            o.z = acc[i][2] + bb.z; o.w = acc[i][3] + bb.w;
            *(float4*)(C + (size_t)row * ldC + col0 + mc) = o;
        }
    }
}

// ---------------------------------------------------------------------------
// CSR construction (graph is static; built once per launch, used 3x)
// ---------------------------------------------------------------------------
__global__ __launch_bounds__(256) void count_deg(const int* __restrict__ dst,
                                                 int* __restrict__ deg)
{
    const int e = blockIdx.x * 256 + threadIdx.x;
    if (e < GE) atomicAdd(&deg[dst[e]], 1);
}

// Block scan: 1024 elements/block (256 threads x 4). Writes exclusive-within-
// block prefix to excl[], block total to blockSums[].
__global__ __launch_bounds__(256) void scan_pass1(const int* __restrict__ deg,
                                                  int* __restrict__ excl,
                                                  int* __restrict__ blockSums)
{
    __shared__ int s[256];
    const int t = threadIdx.x;
    const int base = blockIdx.x * 1024 + t * 4;

    int4 v = make_int4(0, 0, 0, 0);
    if (base + 3 < GN) {
        v = *(const int4*)(deg + base);
    } else {
        if (base + 0 < GN) v.x = deg[base + 0];
        if (base + 1 < GN) v.y = deg[base + 1];
        if (base + 2 < GN) v.z = deg[base + 2];
        if (base + 3 < GN) v.w = deg[base + 3];
    }
    const int mysum = v.x + v.y + v.z + v.w;
    s[t] = mysum;
    __syncthreads();
    for (int off = 1; off < 256; off <<= 1) {
        const int val = (t >= off) ? s[t - off] : 0;
        __syncthreads();
        s[t] += val;
        __syncthreads();
    }
    int4 o;
    o.x = s[t] - mysum;
    o.y = o.x + v.x;
    o.z = o.y + v.y;
    o.w = o.z + v.z;
    if (base + 3 < GN) {
        *(int4*)(excl + base) = o;
    } else {
        if (base + 0 < GN) excl[base + 0] = o.x;
        if (base + 1 < GN) excl[base + 1] = o.y;
        if (base + 2 < GN) excl[base + 2] = o.z;
        if (base + 3 < GN) excl[base + 3] = o.w;
    }
    if (t == 255) blockSums[blockIdx.x] = s[255];
}

__global__ __launch_bounds__(128) void scan_pass2(const int* __restrict__ blockSums,
                                                  int* __restrict__ blockOffs, int n)
{
    __shared__ int s[128];
    const int t = threadIdx.x;
    const int v = (t < n) ? blockSums[t] : 0;
    s[t] = v;
    __syncthreads();
    for (int off = 1; off < 128; off <<= 1) {
        const int val = (t >= off) ? s[t - off] : 0;
        __syncthreads();
        s[t] += val;
        __syncthreads();
    }
    if (t < n) blockOffs[t] = s[t] - v;
}

__global__ __launch_bounds__(256) void scan_pass3(int* __restrict__ excl,
                                                  const int* __restrict__ blockOffs,
                                                  int* __restrict__ cursor)
{
    const int i = blockIdx.x * 256 + threadIdx.x;
    if (i >= GN) return;
    const int v = excl[i] + blockOffs[i >> 10];   // scan1 blocks covered 1024 elems
    excl[i]   = v;   // row_start
    cursor[i] = v;   // running cursor for fill
}

__global__ __launch_bounds__(256) void fill_csr(const int* __restrict__ src,
                                                const int* __restrict__ dst,
                                                int* __restrict__ cursor,
                                                int* __restrict__ csr)
{
    const int e = blockIdx.x * 256 + threadIdx.x;
    if (e >= GE) return;
    const int pos = atomicAdd(&cursor[dst[e]], 1);
    csr[pos] = src[e];
}

// ---------------------------------------------------------------------------
// agg[v] = h[v] + sum_{e in CSR row v} h[csr[e]]
// one wave (64 lanes) per node; each lane owns a float2 (64*8B = 512B row)
// h lives inside cat buffer with leading dim 512; agg is dense [GN,128]
// ---------------------------------------------------------------------------
__global__ __launch_bounds__(256) void gather_agg(
    const float* __restrict__ h,          // ld 512
    const int* __restrict__ row_start,
    const int* __restrict__ deg,
    const int* __restrict__ csr,
    float* __restrict__ agg)              // [GN,128]
{
    const int w    = (blockIdx.x * 256 + threadIdx.x) >> 6;  // node id
    const int lane = threadIdx.x & 63;
    if (w >= GN) return;
    const int j = lane * 2;

    float2 acc = *(const float2*)(h + (size_t)w * 512 + j);  // self term
    const int start = row_start[w];
    const int n     = deg[w];
    for (int k = 0; k < n; ++k) {
        const int s = csr[start + k];
        const float2 t = *(const float2*)(h + (size_t)s * 512 + j);
        acc.x += t.x; acc.y += t.y;
    }
    *(float2*)(agg + (size_t)w * 128 + j) = acc;
}

// ---------------------------------------------------------------------------
// in-place softmax over rows of 64; one wave per row
// ---------------------------------------------------------------------------
__global__ __launch_bounds__(256) void softmax64(float* __restrict__ out)
{
    const int w = (blockIdx.x * blockDim.x + threadIdx.x) >> 6;
    const int lane = threadIdx.x & 63;
    if (w >= GN) return;
    float* p = out + (size_t)w * 64;
    const float v = p[lane];
    float m = v;
#pragma unroll
    for (int off = 32; off > 0; off >>= 1) m = fmaxf(m, __shfl_xor(m, off));
    const float e = __expf(v - m);
    float s = e;
#pragma unroll
    for (int off = 32; off > 0; off >>= 1) s += __shfl_xor(s, off);
    p[lane] = e / s;
}

extern "C" void kernel_launch(void* const* d_in, const int* in_sizes, int n_in,
                              void* d_out, int out_size, void* d_ws, size_t ws_size,
                              hipStream_t stream)
{
    const float* x       = (const float*)d_in[0];
    const int*   src     = (const int*)d_in[1];            // edge_index[0]
    const int*   dst     = ((const int*)d_in[1]) + GE;     // edge_index[1]
    const float* W_in    = (const float*)d_in[2];
    const float* b_in    = (const float*)d_in[3];
    const float* W_convs = (const float*)d_in[4];          // [3,128,128]
    const float* b_convs = (const float*)d_in[5];          // [3,128]
    const float* W_out   = (const float*)d_in[6];          // [64,512]
    const float* b_out   = (const float*)d_in[7];
    float*       out     = (float*)d_out;                  // [GN,64]

    // d_ws: cat [GN,512] fp32 (hidden states as concat blocks) + agg [GN,128]
    float* cat = (float*)d_ws;
    float* agg = cat + (size_t)GN * 512;

    // CSR scratch lives in d_out (25.6 MB, 3.6 MB needed) — it is dead storage
    // until the final GEMM, which runs after the last gather and overwrites it.
    int* deg       = (int*)d_out;
    int* row_start = deg + GN;
    int* cursor    = row_start + GN;
    int* blockSums = cursor + GN;
    int* blockOffs = blockSums + 128;
    int* csr       = blockOffs + 128;

    const dim3 blk(256);
    const dim3 g128((GN + 63) / 64, 128 / 64);
    const dim3 g64((GN + 63) / 64, 1);
    const int edge_blocks    = (GE + 255) / 256;
    const int node_blocks    = (GN + 255) / 256;
    const int gather_blocks  = (GN + 3) / 4;     // 4 waves/block, 1 node/wave
    const int softmax_blocks = (GN + 3) / 4;

    // --- CSR build (graph static; reused by all 3 layers) ---
    hipMemsetAsync(deg, 0, GN * sizeof(int), stream);
    count_deg<<<edge_blocks, blk, 0, stream>>>(dst, deg);
    scan_pass1<<<SCAN_NBLK, blk, 0, stream>>>(deg, row_start, blockSums);
    scan_pass2<<<1, 128, 0, stream>>>(blockSums, blockOffs, SCAN_NBLK);
    scan_pass3<<<node_blocks, blk, 0, stream>>>(row_start, blockOffs, cursor);
    fill_csr<<<edge_blocks, blk, 0, stream>>>(src, dst, cursor, csr);

    // --- input projection -> cat block 0 ---
    gemm_bias<<<g128, blk, 0, stream>>>(x, 128, W_in, b_in, cat, 512, GN, 128, 128);

    // --- three GIN layers: gather (self + neighbors), then linear ---
    for (int i = 0; i < 3; ++i) {
        const float* h = cat + i * 128;          // current hidden block, ld 512
        gather_agg<<<gather_blocks, blk, 0, stream>>>(h, row_start, deg, csr, agg);
        gemm_bias<<<g128, blk, 0, stream>>>(agg, 128,
                                            W_convs + (size_t)i * 128 * 128,
                                            b_convs + (size_t)i * 128,
                                            cat + (i + 1) * 128, 512, GN, 128, 128);
    }

    // --- output projection (reads full cat, ld 512) -> d_out, softmax in-place ---
    gemm_bias<<<g64, blk, 0, stream>>>(cat, 512, W_out, b_out, out, 64, GN, 64, 512);
    softmax64<<<softmax_blocks, blk, 0, stream>>>(out);
}

// Round 3
// 683.630 us; speedup vs baseline: 5.2219x; 1.1273x over previous
//
#include <hip/hip_runtime.h>
#include <hip/hip_bf16.h>

#define GN 100000
#define GE 600000
#define SCAN_NBLK 98   // ceil(GN / 1024)

typedef __bf16 bf16x8 __attribute__((ext_vector_type(8)));
typedef __bf16 bf16x4 __attribute__((ext_vector_type(4)));
typedef float  f32x4  __attribute__((ext_vector_type(4)));

// ---------------------------------------------------------------------------
// Split-precision MFMA GEMM: C[M, BN] = A[M, K] @ W[BN, K]^T + bias
// fp32 in/out; internally a = hi(bf16) + lo(bf16), 3-term MFMA (hi*hi + hi*lo
// + lo*hi) with fp32 accumulation -> ~2^-17 relative error (fp32-equivalent
// under the harness's bf16-granularity compare).
// Block 512 threads = 8 waves, wave tile 32x32 (2x2 MFMA 16x16x32 tiles).
// BN = full OC (128 or 64) -> single column pass, A read once from HBM.
// A-tile [BM x 64] staged in LDS as hi/lo bf16 (pad 72 -> 2-way-free banks);
// W fragments loaded straight from global fp32 (L1/L2-hot) + converted.
// ---------------------------------------------------------------------------
template<int BN>
__global__ __launch_bounds__(512, 2) void gemm_mfma(
    const float* __restrict__ A, int ldA,
    const float* __restrict__ W, int ldW,    // [BN, K] row-major, ldW == K
    const float* __restrict__ bias,          // [BN]
    float* __restrict__ C, int ldC,
    int M, int K)
{
    constexpr int NG = BN / 32;        // n wave-groups (4 or 2)
    constexpr int MG = 8 / NG;         // m wave-groups (2 or 4)
    constexpr int BM = MG * 32;        // 64 or 128
    constexpr int LDS_LD = 72;         // bf16 per LDS row: 64 + 8 pad

    __shared__ __bf16 Ahi[BM * LDS_LD];
    __shared__ __bf16 Alo[BM * LDS_LD];

    const int tid   = threadIdx.x;
    const int wave  = tid >> 6;
    const int lane  = tid & 63;
    const int row0  = blockIdx.x * BM;

    const int wm    = (wave / NG) * 32;  // wave m-offset in block tile
    const int wn    = (wave % NG) * 32;  // wave n-offset
    const int quad  = lane >> 4;         // 0..3
    const int l15   = lane & 15;

    f32x4 acc[2][2];
#pragma unroll
    for (int i = 0; i < 2; ++i)
#pragma unroll
        for (int j = 0; j < 2; ++j) acc[i][j] = (f32x4)(0.0f);

    for (int k0 = 0; k0 < K; k0 += 64) {
        // ---- stage A chunk [BM x 64] fp32 -> hi/lo bf16 in LDS ----
#pragma unroll
        for (int j = 0; j < BM / 32; ++j) {
            const int f  = tid * 4 + j * 2048;   // flat float index in chunk
            const int r  = f >> 6;               // row in tile
            const int kc = f & 63;               // k offset (multiple of 4)
            float4 v = make_float4(0.f, 0.f, 0.f, 0.f);
            const int gr = row0 + r;
            if (gr < M) v = *(const float4*)(A + (size_t)gr * ldA + k0 + kc);
            const __bf16 h0 = (__bf16)v.x, h1 = (__bf16)v.y,
                         h2 = (__bf16)v.z, h3 = (__bf16)v.w;
            const int idx = r * LDS_LD + kc;
            *(bf16x4*)&Ahi[idx] = (bf16x4){h0, h1, h2, h3};
            *(bf16x4*)&Alo[idx] = (bf16x4){(__bf16)(v.x - (float)h0),
                                           (__bf16)(v.y - (float)h1),
                                           (__bf16)(v.z - (float)h2),
                                           (__bf16)(v.w - (float)h3)};
        }
        __syncthreads();

#pragma unroll
        for (int ks = 0; ks < 2; ++ks) {
            const int kl = ks * 32 + quad * 8;   // k within LDS tile

            // A fragments from LDS (16B aligned: 144-byte rows, kl*2 mult of 16)
            bf16x8 a_hi[2], a_lo[2];
#pragma unroll
            for (int mt = 0; mt < 2; ++mt) {
                const int idx = (wm + mt * 16 + l15) * LDS_LD + kl;
                a_hi[mt] = *(const bf16x8*)&Ahi[idx];
                a_lo[mt] = *(const bf16x8*)&Alo[idx];
            }

            // W fragments from global fp32 (cache-hot), convert to hi/lo
            bf16x8 w_hi[2], w_lo[2];
#pragma unroll
            for (int nt = 0; nt < 2; ++nt) {
                const int n  = wn + nt * 16 + l15;
                const float* wp = W + (size_t)n * ldW + k0 + kl;
                const float4 p = *(const float4*)(wp);
                const float4 q = *(const float4*)(wp + 4);
                float pv[8] = {p.x, p.y, p.z, p.w, q.x, q.y, q.z, q.w};
#pragma unroll
                for (int e = 0; e < 8; ++e) {
                    const __bf16 h = (__bf16)pv[e];
                    w_hi[nt][e] = h;
                    w_lo[nt][e] = (__bf16)(pv[e] - (float)h);
                }
            }

            // 3-term split MFMAs
#pragma unroll
            for (int mt = 0; mt < 2; ++mt)
#pragma unroll
                for (int nt = 0; nt < 2; ++nt) {
                    acc[mt][nt] = __builtin_amdgcn_mfma_f32_16x16x32_bf16(
                        a_hi[mt], w_hi[nt], acc[mt][nt], 0, 0, 0);
                    acc[mt][nt] = __builtin_amdgcn_mfma_f32_16x16x32_bf16(
                        a_hi[mt], w_lo[nt], acc[mt][nt], 0, 0, 0);
                    acc[mt][nt] = __builtin_amdgcn_mfma_f32_16x16x32_bf16(
                        a_lo[mt], w_hi[nt], acc[mt][nt], 0, 0, 0);
                }
        }
        __syncthreads();
    }

    // epilogue: D layout row=(lane>>4)*4+reg, col=lane&15
#pragma unroll
    for (int nt = 0; nt < 2; ++nt) {
        const int col = wn + nt * 16 + l15;
        const float b = bias[col];
#pragma unroll
        for (int mt = 0; mt < 2; ++mt) {
#pragma unroll
            for (int r = 0; r < 4; ++r) {
                const int row = row0 + wm + mt * 16 + quad * 4 + r;
                if (row < M) C[(size_t)row * ldC + col] = acc[mt][nt][r] + b;
            }
        }
    }
}

// ---------------------------------------------------------------------------
// CSR construction (graph static; built once per launch, used 3x)
// ---------------------------------------------------------------------------
__global__ __launch_bounds__(256) void count_deg(const int* __restrict__ dst,
                                                 int* __restrict__ deg)
{
    const int e = blockIdx.x * 256 + threadIdx.x;
    if (e < GE) atomicAdd(&deg[dst[e]], 1);
}

__global__ __launch_bounds__(256) void scan_pass1(const int* __restrict__ deg,
                                                  int* __restrict__ excl,
                                                  int* __restrict__ blockSums)
{
    __shared__ int s[256];
    const int t = threadIdx.x;
    const int base = blockIdx.x * 1024 + t * 4;

    int4 v = make_int4(0, 0, 0, 0);
    if (base + 3 < GN) {
        v = *(const int4*)(deg + base);
    } else {
        if (base + 0 < GN) v.x = deg[base + 0];
        if (base + 1 < GN) v.y = deg[base + 1];
        if (base + 2 < GN) v.z = deg[base + 2];
        if (base + 3 < GN) v.w = deg[base + 3];
    }
    const int mysum = v.x + v.y + v.z + v.w;
    s[t] = mysum;
    __syncthreads();
    for (int off = 1; off < 256; off <<= 1) {
        const int val = (t >= off) ? s[t - off] : 0;
        __syncthreads();
        s[t] += val;
        __syncthreads();
    }
    int4 o;
    o.x = s[t] - mysum;
    o.y = o.x + v.x;
    o.z = o.y + v.y;
    o.w = o.z + v.z;
    if (base + 3 < GN) {
        *(int4*)(excl + base) = o;
    } else {
        if (base + 0 < GN) excl[base + 0] = o.x;
        if (base + 1 < GN) excl[base + 1] = o.y;
        if (base + 2 < GN) excl[base + 2] = o.z;
        if (base + 3 < GN) excl[base + 3] = o.w;
    }
    if (t == 255) blockSums[blockIdx.x] = s[255];
}

__global__ __launch_bounds__(128) void scan_pass2(const int* __restrict__ blockSums,
                                                  int* __restrict__ blockOffs, int n)
{
    __shared__ int s[128];
    const int t = threadIdx.x;
    const int v = (t < n) ? blockSums[t] : 0;
    s[t] = v;
    __syncthreads();
    for (int off = 1; off < 128; off <<= 1) {
        const int val = (t >= off) ? s[t - off] : 0;
        __syncthreads();
        s[t] += val;
        __syncthreads();
    }
    if (t < n) blockOffs[t] = s[t] - v;
}

__global__ __launch_bounds__(256) void scan_pass3(int* __restrict__ excl,
                                                  const int* __restrict__ blockOffs,
                                                  int* __restrict__ cursor)
{
    const int i = blockIdx.x * 256 + threadIdx.x;
    if (i >= GN) return;
    const int v = excl[i] + blockOffs[i >> 10];
    excl[i]   = v;   // row_start
    cursor[i] = v;   // running cursor for fill
}

__global__ __launch_bounds__(256) void fill_csr(const int* __restrict__ src,
                                                const int* __restrict__ dst,
                                                int* __restrict__ cursor,
                                                int* __restrict__ csr)
{
    const int e = blockIdx.x * 256 + threadIdx.x;
    if (e >= GE) return;
    const int pos = atomicAdd(&cursor[dst[e]], 1);
    csr[pos] = src[e];
}

// ---------------------------------------------------------------------------
// agg[v] = h[v] + sum_{e in CSR row v} h[csr[e]]
// one wave per node; each lane owns a float2 (64*8B = 512B row)
// ---------------------------------------------------------------------------
__global__ __launch_bounds__(256) void gather_agg(
    const float* __restrict__ h,          // ld 512
    const int* __restrict__ row_start,
    const int* __restrict__ deg,
    const int* __restrict__ csr,
    float* __restrict__ agg)              // [GN,128]
{
    const int w    = (blockIdx.x * 256 + threadIdx.x) >> 6;
    const int lane = threadIdx.x & 63;
    if (w >= GN) return;
    const int j = lane * 2;

    float2 acc = *(const float2*)(h + (size_t)w * 512 + j);
    const int start = row_start[w];
    const int n     = deg[w];
    for (int k = 0; k < n; ++k) {
        const int s = csr[start + k];
        const float2 t = *(const float2*)(h + (size_t)s * 512 + j);
        acc.x += t.x; acc.y += t.y;
    }
    *(float2*)(agg + (size_t)w * 128 + j) = acc;
}

// ---------------------------------------------------------------------------
// in-place softmax over rows of 64; one wave per row
// ---------------------------------------------------------------------------
__global__ __launch_bounds__(256) void softmax64(float* __restrict__ out)
{
    const int w = (blockIdx.x * blockDim.x + threadIdx.x) >> 6;
    const int lane = threadIdx.x & 63;
    if (w >= GN) return;
    float* p = out + (size_t)w * 64;
    const float v = p[lane];
    float m = v;
#pragma unroll
    for (int off = 32; off > 0; off >>= 1) m = fmaxf(m, __shfl_xor(m, off));
    const float e = __expf(v - m);
    float s = e;
#pragma unroll
    for (int off = 32; off > 0; off >>= 1) s += __shfl_xor(s, off);
    p[lane] = e / s;
}

extern "C" void kernel_launch(void* const* d_in, const int* in_sizes, int n_in,
                              void* d_out, int out_size, void* d_ws, size_t ws_size,
                              hipStream_t stream)
{
    const float* x       = (const float*)d_in[0];
    const int*   src     = (const int*)d_in[1];            // edge_index[0]
    const int*   dst     = ((const int*)d_in[1]) + GE;     // edge_index[1]
    const float* W_in    = (const float*)d_in[2];
    const float* b_in    = (const float*)d_in[3];
    const float* W_convs = (const float*)d_in[4];          // [3,128,128]
    const float* b_convs = (const float*)d_in[5];          // [3,128]
    const float* W_out   = (const float*)d_in[6];          // [64,512]
    const float* b_out   = (const float*)d_in[7];
    float*       out     = (float*)d_out;                  // [GN,64]

    // d_ws: cat [GN,512] fp32 (hidden states as concat blocks) + agg [GN,128]
    float* cat = (float*)d_ws;
    float* agg = cat + (size_t)GN * 512;

    // CSR scratch in d_out (dead until final GEMM overwrites it)
    int* deg       = (int*)d_out;
    int* row_start = deg + GN;
    int* cursor    = row_start + GN;
    int* blockSums = cursor + GN;
    int* blockOffs = blockSums + 128;
    int* csr       = blockOffs + 128;

    const dim3 blk(256);
    const dim3 gblk(512);
    const int edge_blocks    = (GE + 255) / 256;
    const int node_blocks    = (GN + 255) / 256;
    const int gather_blocks  = (GN + 3) / 4;
    const int softmax_blocks = (GN + 3) / 4;
    const int gemm128_blocks = (GN + 63) / 64;    // BM=64 for BN=128
    const int gemm64_blocks  = (GN + 127) / 128;  // BM=128 for BN=64

    // --- CSR build (graph static; reused by all 3 layers) ---
    hipMemsetAsync(deg, 0, GN * sizeof(int), stream);
    count_deg<<<edge_blocks, blk, 0, stream>>>(dst, deg);
    scan_pass1<<<SCAN_NBLK, blk, 0, stream>>>(deg, row_start, blockSums);
    scan_pass2<<<1, 128, 0, stream>>>(blockSums, blockOffs, SCAN_NBLK);
    scan_pass3<<<node_blocks, blk, 0, stream>>>(row_start, blockOffs, cursor);
    fill_csr<<<edge_blocks, blk, 0, stream>>>(src, dst, cursor, csr);

    // --- input projection -> cat block 0 ---
    gemm_mfma<128><<<gemm128_blocks, gblk, 0, stream>>>(
        x, 128, W_in, 128, b_in, cat, 512, GN, 128);

    // --- three GIN layers: gather (self + neighbors), then linear ---
    for (int i = 0; i < 3; ++i) {
        const float* h = cat + i * 128;
        gather_agg<<<gather_blocks, blk, 0, stream>>>(h, row_start, deg, csr, agg);
        gemm_mfma<128><<<gemm128_blocks, gblk, 0, stream>>>(
            agg, 128, W_convs + (size_t)i * 128 * 128, 128,
            b_convs + (size_t)i * 128, cat + (i + 1) * 128, 512, GN, 128);
    }

    // --- output projection (reads full cat) -> d_out, softmax in-place ---
    gemm_mfma<64><<<gemm64_blocks, gblk, 0, stream>>>(
        cat, 512, W_out, 512, b_out, out, 64, GN, 512);
    softmax64<<<softmax_blocks, blk, 0, stream>>>(out);
}

// Round 4
// 601.307 us; speedup vs baseline: 5.9368x; 1.1369x over previous
//
#include <hip/hip_runtime.h>
#include <hip/hip_bf16.h>

#define GN 100000
#define GE 600000
#define SCAN_NBLK 98   // ceil(GN / 1024)

typedef __bf16 bf16x8 __attribute__((ext_vector_type(8)));
typedef __bf16 bf16x4 __attribute__((ext_vector_type(4)));
typedef __bf16 bf16x2 __attribute__((ext_vector_type(2)));
typedef float  f32x4  __attribute__((ext_vector_type(4)));

// ---------------------------------------------------------------------------
// Weight pre-conversion: fp32 -> (hi, lo) bf16 planes, done ONCE per launch.
// Layout in planes: [0,16384) = W_in[128,128]; [16384,65536) = W_convs[3][128][128];
// [65536,98304) = W_out[64,512]. All row-major [OC, K].
// ---------------------------------------------------------------------------
__global__ __launch_bounds__(256) void convert_w(
    const float* __restrict__ Win, const float* __restrict__ Wc,
    const float* __restrict__ Wout,
    __bf16* __restrict__ hi, __bf16* __restrict__ lo)
{
    const int i = blockIdx.x * 256 + threadIdx.x;
    if (i >= 98304) return;
    float v;
    if (i < 16384)      v = Win[i];
    else if (i < 65536) v = Wc[i - 16384];
    else                v = Wout[i - 65536];
    const __bf16 h = (__bf16)v;
    hi[i] = h;
    lo[i] = (__bf16)(v - (float)h);
}

// ---------------------------------------------------------------------------
// Fused GIN layer: C[64-row tile, 128] = (gather(H) if GATHER else H) @ W^T + b
// Phase A: gather self+neighbors (fp32 accumulate) -> split hi/lo bf16 in LDS.
// Phase B: 3-term split MFMA (hi*hi + hi*lo + lo*hi), K=128, W pre-converted.
// Phase C: acc -> LDS fp32 -> full-row 512B coalesced float4 stores (avoids
//          write-allocate fetches seen with 64B store segments).
// Block 512 = 8 waves; wave tile 32x32; BM=64, BN=128.
// ---------------------------------------------------------------------------
template<bool GATHER>
__global__ __launch_bounds__(512, 2) void gin_layer(
    const float* __restrict__ H, int ldH,
    const int* __restrict__ row_start,
    const int* __restrict__ deg,
    const int* __restrict__ csr,
    const __bf16* __restrict__ Whi,   // [128,128]
    const __bf16* __restrict__ Wlo,
    const float* __restrict__ bias,   // [128]
    float* __restrict__ C, int ldC)
{
    constexpr int K   = 128;
    constexpr int ALD = 136;   // bf16 LDS ld: 128 + 8 (16B-aligned rows, 2-way-free banks)
    constexpr int CLD = 132;   // fp32 epilogue ld: 128 + 4 (quad bank shift)

    __shared__ char smem_raw[64 * ALD * 2 * 2];   // 34816 B
    __bf16* Ahi = (__bf16*)smem_raw;
    __bf16* Alo = Ahi + 64 * ALD;
    float*  Cst = (float*)smem_raw;               // 64*132*4 = 33792 B (reused)

    const int tid  = threadIdx.x;
    const int wave = tid >> 6;
    const int lane = tid & 63;
    const int row0 = blockIdx.x * 64;
    const int wm   = (wave >> 2) * 32;   // 0/32
    const int wn   = (wave & 3) * 32;    // 0/32/64/96
    const int quad = lane >> 4;
    const int l15  = lane & 15;

    // ---- Phase A: build A-tile (hi/lo bf16) in LDS ----
    if (GATHER) {
        const int j = lane * 2;          // lane owns float2 of the 128-dim row
        for (int i = 0; i < 8; ++i) {
            const int r = wave * 8 + i;
            const int v = row0 + r;
            float2 a2 = make_float2(0.f, 0.f);
            if (v < GN) {
                a2 = *(const float2*)(H + (size_t)v * ldH + j);   // self term
                const int st = row_start[v];
                const int n  = deg[v];
                int k = 0;
                for (; k + 1 < n; k += 2) {                        // 2-wide for MLP
                    const int s0 = csr[st + k];
                    const int s1 = csr[st + k + 1];
                    const float2 t0 = *(const float2*)(H + (size_t)s0 * ldH + j);
                    const float2 t1 = *(const float2*)(H + (size_t)s1 * ldH + j);
                    a2.x += t0.x + t1.x;
                    a2.y += t0.y + t1.y;
                }
                if (k < n) {
                    const int s0 = csr[st + k];
                    const float2 t0 = *(const float2*)(H + (size_t)s0 * ldH + j);
                    a2.x += t0.x; a2.y += t0.y;
                }
            }
            const __bf16 h0 = (__bf16)a2.x, h1 = (__bf16)a2.y;
            const int idx = r * ALD + j;
            *(bf16x2*)&Ahi[idx] = (bf16x2){h0, h1};
            *(bf16x2*)&Alo[idx] = (bf16x2){(__bf16)(a2.x - (float)h0),
                                           (__bf16)(a2.y - (float)h1)};
        }
    } else {
#pragma unroll
        for (int p = 0; p < 4; ++p) {
            const int q  = tid + p * 512;
            const int f  = q * 4;
            const int r  = f >> 7;       // 128 floats per row
            const int kc = f & 127;
            float4 v4 = make_float4(0.f, 0.f, 0.f, 0.f);
            const int gr = row0 + r;
            if (gr < GN) v4 = *(const float4*)(H + (size_t)gr * ldH + kc);
            const __bf16 h0 = (__bf16)v4.x, h1 = (__bf16)v4.y,
                         h2 = (__bf16)v4.z, h3 = (__bf16)v4.w;
            const int idx = r * ALD + kc;
            *(bf16x4*)&Ahi[idx] = (bf16x4){h0, h1, h2, h3};
            *(bf16x4*)&Alo[idx] = (bf16x4){(__bf16)(v4.x - (float)h0),
                                           (__bf16)(v4.y - (float)h1),
                                           (__bf16)(v4.z - (float)h2),
                                           (__bf16)(v4.w - (float)h3)};
        }
    }
    __syncthreads();

    // ---- Phase B: MFMA ----
    f32x4 acc[2][2];
#pragma unroll
    for (int i = 0; i < 2; ++i)
#pragma unroll
        for (int j = 0; j < 2; ++j) acc[i][j] = (f32x4)(0.0f);

#pragma unroll
    for (int ks = 0; ks < 4; ++ks) {
        const int kt = ks * 32 + quad * 8;
        bf16x8 ahi[2], alo[2];
#pragma unroll
        for (int mt = 0; mt < 2; ++mt) {
            const int idx = (wm + mt * 16 + l15) * ALD + kt;
            ahi[mt] = *(const bf16x8*)&Ahi[idx];
            alo[mt] = *(const bf16x8*)&Alo[idx];
        }
        bf16x8 whi[2], wlo[2];
#pragma unroll
        for (int nt = 0; nt < 2; ++nt) {
            const int n = wn + nt * 16 + l15;
            whi[nt] = *(const bf16x8*)(Whi + (size_t)n * K + kt);
            wlo[nt] = *(const bf16x8*)(Wlo + (size_t)n * K + kt);
        }
#pragma unroll
        for (int mt = 0; mt < 2; ++mt)
#pragma unroll
            for (int nt = 0; nt < 2; ++nt) {
                acc[mt][nt] = __builtin_amdgcn_mfma_f32_16x16x32_bf16(
                    ahi[mt], whi[nt], acc[mt][nt], 0, 0, 0);
                acc[mt][nt] = __builtin_amdgcn_mfma_f32_16x16x32_bf16(
                    ahi[mt], wlo[nt], acc[mt][nt], 0, 0, 0);
                acc[mt][nt] = __builtin_amdgcn_mfma_f32_16x16x32_bf16(
                    alo[mt], whi[nt], acc[mt][nt], 0, 0, 0);
            }
    }
    __syncthreads();

    // ---- Phase C: epilogue via LDS, full-row coalesced stores ----
#pragma unroll
    for (int nt = 0; nt < 2; ++nt) {
        const int col = wn + nt * 16 + l15;
        const float b = bias[col];
#pragma unroll
        for (int mt = 0; mt < 2; ++mt)
#pragma unroll
            for (int r4 = 0; r4 < 4; ++r4)
                Cst[(wm + mt * 16 + quad * 4 + r4) * CLD + col] = acc[mt][nt][r4] + b;
    }
    __syncthreads();
#pragma unroll
    for (int p = 0; p < 4; ++p) {
        const int q  = tid + p * 512;
        const int r  = q >> 5;           // 32 float4 per row
        const int c4 = (q & 31) * 4;
        const int gr = row0 + r;
        if (gr < GN)
            *(float4*)(C + (size_t)gr * ldC + c4) = *(const float4*)&Cst[r * CLD + c4];
    }
}

// ---------------------------------------------------------------------------
// Final projection + fused softmax: out[GN,64] = softmax(cat @ W_out^T + b)
// BM=128, BN=64 (full row per block), K=512 in BK=64 chunks.
// ---------------------------------------------------------------------------
__global__ __launch_bounds__(512, 2) void final_gemm_softmax(
    const float* __restrict__ A,        // cat, ld 512
    const __bf16* __restrict__ Whi,     // [64,512]
    const __bf16* __restrict__ Wlo,
    const float* __restrict__ bias,     // [64]
    float* __restrict__ out)            // [GN,64]
{
    constexpr int K   = 512;
    constexpr int ALD = 72;    // 64 + 8
    constexpr int CLD = 68;    // 64 + 4

    __shared__ char smem_raw[128 * ALD * 2 * 2];   // 36864 B
    __bf16* Ahi = (__bf16*)smem_raw;
    __bf16* Alo = Ahi + 128 * ALD;
    float*  Cst = (float*)smem_raw;                // 128*68*4 = 34816 B

    const int tid  = threadIdx.x;
    const int wave = tid >> 6;
    const int lane = tid & 63;
    const int row0 = blockIdx.x * 128;
    const int wm   = (wave >> 1) * 32;   // 0/32/64/96
    const int wn   = (wave & 1) * 32;    // 0/32
    const int quad = lane >> 4;
    const int l15  = lane & 15;

    f32x4 acc[2][2];
#pragma unroll
    for (int i = 0; i < 2; ++i)
#pragma unroll
        for (int j = 0; j < 2; ++j) acc[i][j] = (f32x4)(0.0f);

    for (int k0 = 0; k0 < K; k0 += 64) {
#pragma unroll
        for (int p = 0; p < 4; ++p) {
            const int q  = tid + p * 512;
            const int f  = q * 4;
            const int r  = f >> 6;       // 64 floats per row-chunk
            const int kc = f & 63;
            float4 v4 = make_float4(0.f, 0.f, 0.f, 0.f);
            const int gr = row0 + r;
            if (gr < GN) v4 = *(const float4*)(A + (size_t)gr * 512 + k0 + kc);
            const __bf16 h0 = (__bf16)v4.x, h1 = (__bf16)v4.y,
                         h2 = (__bf16)v4.z, h3 = (__bf16)v4.w;
            const int idx = r * ALD + kc;
            *(bf16x4*)&Ahi[idx] = (bf16x4){h0, h1, h2, h3};
            *(bf16x4*)&Alo[idx] = (bf16x4){(__bf16)(v4.x - (float)h0),
                                           (__bf16)(v4.y - (float)h1),
                                           (__bf16)(v4.z - (float)h2),
                                           (__bf16)(v4.w - (float)h3)};
        }
        __syncthreads();

#pragma unroll
        for (int ks = 0; ks < 2; ++ks) {
            const int kt = ks * 32 + quad * 8;
            bf16x8 ahi[2], alo[2];
#pragma unroll
            for (int mt = 0; mt < 2; ++mt) {
                const int idx = (wm + mt * 16 + l15) * ALD + kt;
                ahi[mt] = *(const bf16x8*)&Ahi[idx];
                alo[mt] = *(const bf16x8*)&Alo[idx];
            }
            bf16x8 whi[2], wlo[2];
#pragma unroll
            for (int nt = 0; nt < 2; ++nt) {
                const int n = wn + nt * 16 + l15;
                whi[nt] = *(const bf16x8*)(Whi + (size_t)n * K + k0 + kt);
                wlo[nt] = *(const bf16x8*)(Wlo + (size_t)n * K + k0 + kt);
            }
#pragma unroll
            for (int mt = 0; mt < 2; ++mt)
#pragma unroll
                for (int nt = 0; nt < 2; ++nt) {
                    acc[mt][nt] = __builtin_amdgcn_mfma_f32_16x16x32_bf16(
                        ahi[mt], whi[nt], acc[mt][nt], 0, 0, 0);
                    acc[mt][nt] = __builtin_amdgcn_mfma_f32_16x16x32_bf16(
                        ahi[mt], wlo[nt], acc[mt][nt], 0, 0, 0);
                    acc[mt][nt] = __builtin_amdgcn_mfma_f32_16x16x32_bf16(
                        alo[mt], whi[nt], acc[mt][nt], 0, 0, 0);
                }
        }
        __syncthreads();
    }

    // epilogue -> LDS, + bias
#pragma unroll
    for (int nt = 0; nt < 2; ++nt) {
        const int col = wn + nt * 16 + l15;
        const float b = bias[col];
#pragma unroll
        for (int mt = 0; mt < 2; ++mt)
#pragma unroll
            for (int r4 = 0; r4 < 4; ++r4)
                Cst[(wm + mt * 16 + quad * 4 + r4) * CLD + col] = acc[mt][nt][r4] + b;
    }
    __syncthreads();

    // fused softmax: 8 waves x 16 rows, one wave per row, 64 lanes = 64 cols
    for (int i = 0; i < 16; ++i) {
        const int r = wave * 16 + i;
        const float v = Cst[r * CLD + lane];
        float m = v;
#pragma unroll
        for (int off = 32; off > 0; off >>= 1) m = fmaxf(m, __shfl_xor(m, off));
        const float e = __expf(v - m);
        float s = e;
#pragma unroll
        for (int off = 32; off > 0; off >>= 1) s += __shfl_xor(s, off);
        const int gr = row0 + r;
        if (gr < GN) out[(size_t)gr * 64 + lane] = e / s;
    }
}

// ---------------------------------------------------------------------------
// CSR construction (graph static; built once per launch, used 3x)
// ---------------------------------------------------------------------------
__global__ __launch_bounds__(256) void count_deg(const int* __restrict__ dst,
                                                 int* __restrict__ deg)
{
    const int e = blockIdx.x * 256 + threadIdx.x;
    if (e < GE) atomicAdd(&deg[dst[e]], 1);
}

__global__ __launch_bounds__(256) void scan_pass1(const int* __restrict__ deg,
                                                  int* __restrict__ excl,
                                                  int* __restrict__ blockSums)
{
    __shared__ int s[256];
    const int t = threadIdx.x;
    const int base = blockIdx.x * 1024 + t * 4;

    int4 v = make_int4(0, 0, 0, 0);
    if (base + 3 < GN) {
        v = *(const int4*)(deg + base);
    } else {
        if (base + 0 < GN) v.x = deg[base + 0];
        if (base + 1 < GN) v.y = deg[base + 1];
        if (base + 2 < GN) v.z = deg[base + 2];
        if (base + 3 < GN) v.w = deg[base + 3];
    }
    const int mysum = v.x + v.y + v.z + v.w;
    s[t] = mysum;
    __syncthreads();
    for (int off = 1; off < 256; off <<= 1) {
        const int val = (t >= off) ? s[t - off] : 0;
        __syncthreads();
        s[t] += val;
        __syncthreads();
    }
    int4 o;
    o.x = s[t] - mysum;
    o.y = o.x + v.x;
    o.z = o.y + v.y;
    o.w = o.z + v.z;
    if (base + 3 < GN) {
        *(int4*)(excl + base) = o;
    } else {
        if (base + 0 < GN) excl[base + 0] = o.x;
        if (base + 1 < GN) excl[base + 1] = o.y;
        if (base + 2 < GN) excl[base + 2] = o.z;
        if (base + 3 < GN) excl[base + 3] = o.w;
    }
    if (t == 255) blockSums[blockIdx.x] = s[255];
}

__global__ __launch_bounds__(128) void scan_pass2(const int* __restrict__ blockSums,
                                                  int* __restrict__ blockOffs, int n)
{
    __shared__ int s[128];
    const int t = threadIdx.x;
    const int v = (t < n) ? blockSums[t] : 0;
    s[t] = v;
    __syncthreads();
    for (int off = 1; off < 128; off <<= 1) {
        const int val = (t >= off) ? s[t - off] : 0;
        __syncthreads();
        s[t] += val;
        __syncthreads();
    }
    if (t < n) blockOffs[t] = s[t] - v;
}

__global__ __launch_bounds__(256) void scan_pass3(int* __restrict__ excl,
                                                  const int* __restrict__ blockOffs,
                                                  int* __restrict__ cursor)
{
    const int i = blockIdx.x * 256 + threadIdx.x;
    if (i >= GN) return;
    const int v = excl[i] + blockOffs[i >> 10];
    excl[i]   = v;   // row_start
    cursor[i] = v;   // running cursor for fill
}

__global__ __launch_bounds__(256) void fill_csr(const int* __restrict__ src,
                                                const int* __restrict__ dst,
                                                int* __restrict__ cursor,
                                                int* __restrict__ csr)
{
    const int e = blockIdx.x * 256 + threadIdx.x;
    if (e >= GE) return;
    const int pos = atomicAdd(&cursor[dst[e]], 1);
    csr[pos] = src[e];
}

extern "C" void kernel_launch(void* const* d_in, const int* in_sizes, int n_in,
                              void* d_out, int out_size, void* d_ws, size_t ws_size,
                              hipStream_t stream)
{
    const float* x       = (const float*)d_in[0];
    const int*   src     = (const int*)d_in[1];            // edge_index[0]
    const int*   dst     = ((const int*)d_in[1]) + GE;     // edge_index[1]
    const float* W_in    = (const float*)d_in[2];
    const float* b_in    = (const float*)d_in[3];
    const float* W_convs = (const float*)d_in[4];          // [3,128,128]
    const float* b_convs = (const float*)d_in[5];          // [3,128]
    const float* W_out   = (const float*)d_in[6];          // [64,512]
    const float* b_out   = (const float*)d_in[7];
    float*       out     = (float*)d_out;                  // [GN,64]

    // d_ws: cat [GN,512] fp32 + pre-converted weight planes (hi/lo bf16)
    float*  cat = (float*)d_ws;
    __bf16* Whi = (__bf16*)(cat + (size_t)GN * 512);
    __bf16* Wlo = Whi + 98304;

    // CSR scratch in d_out (dead until final kernel overwrites it)
    int* deg       = (int*)d_out;
    int* row_start = deg + GN;
    int* cursor    = row_start + GN;
    int* blockSums = cursor + GN;
    int* blockOffs = blockSums + 128;
    int* csr       = blockOffs + 128;

    const dim3 blk(256);
    const dim3 gblk(512);
    const int edge_blocks  = (GE + 255) / 256;
    const int node_blocks  = (GN + 255) / 256;
    const int layer_blocks = (GN + 63) / 64;     // 1563
    const int final_blocks = (GN + 127) / 128;   // 782

    // --- CSR build (graph static; reused by all 3 layers) ---
    hipMemsetAsync(deg, 0, GN * sizeof(int), stream);
    count_deg<<<edge_blocks, blk, 0, stream>>>(dst, deg);
    scan_pass1<<<SCAN_NBLK, blk, 0, stream>>>(deg, row_start, blockSums);
    scan_pass2<<<1, 128, 0, stream>>>(blockSums, blockOffs, SCAN_NBLK);
    scan_pass3<<<node_blocks, blk, 0, stream>>>(row_start, blockOffs, cursor);
    fill_csr<<<edge_blocks, blk, 0, stream>>>(src, dst, cursor, csr);

    // --- weight pre-conversion (hi/lo bf16 planes) ---
    convert_w<<<(98304 + 255) / 256, blk, 0, stream>>>(W_in, W_convs, W_out, Whi, Wlo);

    // --- input projection -> cat block 0 ---
    gin_layer<false><<<layer_blocks, gblk, 0, stream>>>(
        x, 128, nullptr, nullptr, nullptr, Whi, Wlo, b_in, cat, 512);

    // --- three fused GIN layers (gather + linear in one kernel) ---
    for (int i = 0; i < 3; ++i) {
        gin_layer<true><<<layer_blocks, gblk, 0, stream>>>(
            cat + i * 128, 512, row_start, deg, csr,
            Whi + 16384 + i * 16384, Wlo + 16384 + i * 16384,
            b_convs + (size_t)i * 128, cat + (i + 1) * 128, 512);
    }

    // --- output projection + fused softmax -> d_out ---
    final_gemm_softmax<<<final_blocks, gblk, 0, stream>>>(
        cat, Whi + 65536, Wlo + 65536, b_out, out);
}